// Round 10
// baseline (317.938 us; speedup 1.0000x reference)
//
#include <hip/hip_runtime.h>

// AxisAttention: x(8,256,128,128) -> per (b,w) sequence over h: QKV GEMM, 4-head
// attention (S=128, d=64), proj GEMM, transposed fp32 output.
// All matmuls: v_mfma_f32_16x16x32_f16, fp32 accum.
// v10: L3-FIT CHUNKING. nb capped at 2: per-pass intermediates (xt 64MB + qkv
//      48MB + attnout 16MB = 128MB) fit the 256MB Infinity Cache, so qkv/xt/
//      attnout round-trips stay in L3 instead of HBM (v9 counters: k1 alone
//      pushed 197MB of HBM writes at 2.2TB/s = its entire 108us). Kernels are
//      byte-identical to v9; only the launch chunking changed.

typedef _Float16 h4 __attribute__((ext_vector_type(4)));
typedef _Float16 h8 __attribute__((ext_vector_type(8)));
typedef float f4 __attribute__((ext_vector_type(4)));
typedef unsigned int u4 __attribute__((ext_vector_type(4)));

#define MFMA32(a, b, c) __builtin_amdgcn_mfma_f32_16x16x32_f16((a), (b), (c), 0, 0, 0)

__device__ __forceinline__ void gll16(const _Float16* g, _Float16* l) {
  __builtin_amdgcn_global_load_lds(
      (const __attribute__((address_space(1))) void*)g,
      (__attribute__((address_space(3))) void*)l, 16, 0, 0);
}

// ---------------- prep: W^T fp16 (wqt[f][c], wpt[f][c]) ----------------
__global__ __launch_bounds__(256) void prep_w(const float* __restrict__ Wqkv,
                                              const float* __restrict__ Wproj,
                                              _Float16* __restrict__ wqt,
                                              _Float16* __restrict__ wpt) {
  int i = blockIdx.x * 256 + threadIdx.x;  // 196608 + 65536
  if (i < 768 * 256) {
    int f = i >> 8, c = i & 255;
    wqt[i] = (_Float16)Wqkv[c * 768 + f];
  } else {
    int j = i - 768 * 256;
    int f = j >> 8, c = j & 255;
    wpt[j] = (_Float16)Wproj[c * 256 + f];
  }
}

// ---------------- prep_x: x[b][c][h][w] fp32 -> xt[bl][w*128+h][c] fp16 --------
__global__ __launch_bounds__(256) void prep_x(const float* __restrict__ x,
                                              _Float16* __restrict__ xt,
                                              int b_base) {
  const int h = blockIdx.x, bl = blockIdx.y;
  const int b = b_base + bl;
  const int tid = threadIdx.x;
  __shared__ __align__(16) _Float16 sT[256 * 132];  // 67584 B, pitch 132

  const int wj = tid & 31, cg = tid >> 5;
#pragma unroll
  for (int ci = 0; ci < 32; ++ci) {
    const int c = cg * 32 + ci;
    f4 v = *(const f4*)(x + (((long)b * 256 + c) * 128 + h) * 128 + wj * 4);
    h4 o;
    o[0] = (_Float16)v[0]; o[1] = (_Float16)v[1];
    o[2] = (_Float16)v[2]; o[3] = (_Float16)v[3];
    *(h4*)(sT + c * 132 + wj * 4) = o;
  }
  __syncthreads();

  // phase 2: 512 8x8 register-tile transposes
#pragma unroll
  for (int tt2 = tid; tt2 < 512; tt2 += 256) {
    const int cb = tt2 & 31, wb = tt2 >> 5;
    h8 r[8];
#pragma unroll
    for (int j = 0; j < 8; ++j)
      r[j] = *(const h8*)(sT + (cb * 8 + j) * 132 + wb * 8);
#pragma unroll
    for (int i = 0; i < 8; ++i) {
      h8 o;
#pragma unroll
      for (int j = 0; j < 8; ++j) o[j] = r[j][i];
      const int w = wb * 8 + i;
      *(h8*)(xt + ((long)bl * 16384 + w * 128 + h) * 256 + cb * 8) = o;
    }
  }
}

// ---------------- K1: qkv[f][t'] = Wqkv^T[f][c] * xt[t'][c] + bqkv --------------
// 1D grid 768*nbv XCD-swizzled. Tile 128f x 128t' (t' tile = one w, all h).
// qkv layout: [qi*nb+bl][head][w][h*64+d]
__global__ __launch_bounds__(256, 4) void k1_qkv(const _Float16* __restrict__ xt,
                                                 const _Float16* __restrict__ wqt,
                                                 const float* __restrict__ bqkv,
                                                 _Float16* __restrict__ qkv,
                                                 int nb) {
  const int wg = blockIdx.x;
  const int xcd = wg & 7, gseq = wg >> 3;
  const int ft = gseq % 6, ghi = gseq / 6;
  const int G = ghi * 8 + xcd;          // [0, 128*nbv)
  const int tt = G & 127, bl = G >> 7;  // tile: w = tt, h = 0..127

  const int tid = threadIdx.x;
  const int lane = tid & 63, wv = tid >> 6;
  const int g = lane >> 4, l16 = lane & 15;
  const int wr = wv >> 1, wc = wv & 1;
  const int f0 = ft * 128;

  __shared__ __align__(16) char smem[34816];
  _Float16* sA = (_Float16*)smem;   // [128 f][64]
  _Float16* sB = sA + 128 * 64;     // [128 t'][64]
  _Float16* sO = sA;                // reuse: [128 t'][136]

  f4 acc[4][4];
#pragma unroll
  for (int mt = 0; mt < 4; ++mt)
#pragma unroll
    for (int nt = 0; nt < 4; ++nt)
#pragma unroll
      for (int r = 0; r < 4; ++r) acc[mt][nt][r] = 0.f;

  const _Float16* Ab = wqt + (long)f0 * 256;
  const _Float16* Bb = xt + ((long)bl * 16384 + tt * 128) * 256;
  const int r0 = wv * 32;
  const int rl = lane >> 3, ch = (lane & 7) * 8;

  for (int kc = 0; kc < 4; ++kc) {
    const int c0 = kc * 64;
#pragma unroll
    for (int i = 0; i < 4; ++i) {
      const int row = r0 + i * 8 + rl;
      gll16(Ab + (long)row * 256 + c0 + ch, sA + (r0 + i * 8) * 64);
      gll16(Bb + (long)row * 256 + c0 + ch, sB + (r0 + i * 8) * 64);
    }
    __syncthreads();
#pragma unroll
    for (int ks = 0; ks < 2; ++ks) {
      const int k = ks * 32 + 8 * g;
      h8 af[4], bf[4];
#pragma unroll
      for (int mt = 0; mt < 4; ++mt)
        af[mt] = *(const h8*)(sA + (wr * 64 + mt * 16 + l16) * 64 + k);
#pragma unroll
      for (int nt = 0; nt < 4; ++nt)
        bf[nt] = *(const h8*)(sB + (wc * 64 + nt * 16 + l16) * 64 + k);
#pragma unroll
      for (int mt = 0; mt < 4; ++mt)
#pragma unroll
        for (int nt = 0; nt < 4; ++nt)
          acc[mt][nt] = MFMA32(af[mt], bf[nt], acc[mt][nt]);
    }
    __syncthreads();
  }

  // bias + repack: sO[t'_local][f_local], pitch 136
#pragma unroll
  for (int mt = 0; mt < 4; ++mt) {
    f4 bb = *(const f4*)(bqkv + f0 + wr * 64 + mt * 16 + 4 * g);
#pragma unroll
    for (int nt = 0; nt < 4; ++nt) {
      const int tl = wc * 64 + nt * 16 + l16;
#pragma unroll
      for (int r = 0; r < 4; ++r)
        sO[tl * 136 + wr * 64 + mt * 16 + 4 * g + r] =
            (_Float16)(acc[mt][nt][r] + bb[r]);
    }
  }
  __syncthreads();

  // store: per f-half -> one (qi,head): 16KB contiguous at qkv[...][w=tt][h][d]
  const int hh = tid >> 1, dh = (tid & 1) * 32;
#pragma unroll
  for (int h2 = 0; h2 < 2; ++h2) {
    const int fh = f0 + h2 * 64;
    const int qi = fh >> 8, head = (fh >> 6) & 3;
    _Float16* dst =
        qkv + (((long)(qi * nb + bl) * 4 + head) * 128 + tt) * 8192 + hh * 64 + dh;
    const _Float16* s = sO + hh * 136 + h2 * 64 + dh;
#pragma unroll
    for (int e = 0; e < 4; ++e)
      *(u4*)(dst + e * 8) = *(const u4*)(s + e * 8);
  }
}

// ---------------- K2: attention per (w, head, bl) ----------------
__global__ __launch_bounds__(256) void k2_attn(const _Float16* __restrict__ qkv,
                                               _Float16* __restrict__ attnout,
                                               int nb) {
  const int w = blockIdx.x, head = blockIdx.y, bl = blockIdx.z;
  const int tid = threadIdx.x;
  const int lane = tid & 63, wv = tid >> 6;
  const int g = lane >> 4, l16 = lane & 15;

  __shared__ __align__(16) char smem[(128 * 72 * 2 + 64 * 136) * 2];  // 54272 B
  _Float16* sQ = (_Float16*)smem;
  _Float16* sK = sQ + 128 * 72;
  _Float16* sVT = sK + 128 * 72;
  _Float16* sP = sQ;
  _Float16* sO = sQ;

  const long base = (((long)bl * 4 + head) * 128 + w) * 8192;
  const long QS = (long)nb * 4 * 128 * 8192;
  const _Float16* qg = qkv + base;
  const _Float16* kg = qkv + base + QS;
  const _Float16* vg = qkv + base + 2 * QS;

#pragma unroll
  for (int i = 0; i < 4; ++i) {
    int u = tid + 256 * i;
    int hh = u >> 3, dq = u & 7;
    *(u4*)(sQ + hh * 72 + dq * 8) = *(const u4*)(qg + hh * 64 + dq * 8);
    *(u4*)(sK + hh * 72 + dq * 8) = *(const u4*)(kg + hh * 64 + dq * 8);
  }
  {
    const int hh = tid & 127, dc = tid >> 7;
#pragma unroll
    for (int jj = 0; jj < 4; ++jj) {
      u4 vv = *(const u4*)(vg + hh * 64 + dc * 32 + jj * 8);
      const _Float16* pe = (const _Float16*)&vv;
#pragma unroll
      for (int e = 0; e < 8; ++e)
        sVT[(dc * 32 + jj * 8 + e) * 136 + hh] = pe[e];
    }
  }
  __syncthreads();

  f4 accS[8][2];
  for (int i = 0; i < 8; ++i)
    for (int jt = 0; jt < 2; ++jt)
      for (int r = 0; r < 4; ++r) accS[i][jt][r] = 0.f;
#pragma unroll
  for (int ks = 0; ks < 2; ++ks) {
    const int k = ks * 32 + 8 * g;
    h8 af[8], bf[2];
#pragma unroll
    for (int i = 0; i < 8; ++i)
      af[i] = *(const h8*)(sK + (i * 16 + l16) * 72 + k);
#pragma unroll
    for (int jt = 0; jt < 2; ++jt)
      bf[jt] = *(const h8*)(sQ + (wv * 32 + jt * 16 + l16) * 72 + k);
#pragma unroll
    for (int i = 0; i < 8; ++i)
#pragma unroll
      for (int jt = 0; jt < 2; ++jt)
        accS[i][jt] = MFMA32(af[i], bf[jt], accS[i][jt]);
  }

  float rinv[2];
#pragma unroll
  for (int jt = 0; jt < 2; ++jt) {
    float m = -1e30f;
    for (int i = 0; i < 8; ++i)
      for (int r = 0; r < 4; ++r) m = fmaxf(m, accS[i][jt][r]);
    m = fmaxf(m, __shfl_xor(m, 16));
    m = fmaxf(m, __shfl_xor(m, 32));
    float s = 0.f;
    for (int i = 0; i < 8; ++i)
      for (int r = 0; r < 4; ++r) {
        float p = __expf((accS[i][jt][r] - m) * 0.125f);
        accS[i][jt][r] = p;
        s += p;
      }
    s += __shfl_xor(s, 16);
    s += __shfl_xor(s, 32);
    rinv[jt] = 1.0f / s;
  }

  __syncthreads();
#pragma unroll
  for (int jt = 0; jt < 2; ++jt) {
    const int hq = wv * 32 + jt * 16 + l16;
#pragma unroll
    for (int i = 0; i < 8; ++i) {
      h4 pv;
      pv[0] = (_Float16)accS[i][jt][0];
      pv[1] = (_Float16)accS[i][jt][1];
      pv[2] = (_Float16)accS[i][jt][2];
      pv[3] = (_Float16)accS[i][jt][3];
      *(h4*)(sP + hq * 136 + i * 16 + 4 * g) = pv;
    }
  }
  __syncthreads();

  f4 accO[4][2];
  for (int mt = 0; mt < 4; ++mt)
    for (int jt = 0; jt < 2; ++jt)
      for (int r = 0; r < 4; ++r) accO[mt][jt][r] = 0.f;
#pragma unroll
  for (int i2 = 0; i2 < 4; ++i2) {
    const int k = i2 * 32 + 8 * g;
    h8 av[4], pb[2];
#pragma unroll
    for (int mt = 0; mt < 4; ++mt)
      av[mt] = *(const h8*)(sVT + (mt * 16 + l16) * 136 + k);
#pragma unroll
    for (int jt = 0; jt < 2; ++jt)
      pb[jt] = *(const h8*)(sP + (wv * 32 + jt * 16 + l16) * 136 + k);
#pragma unroll
    for (int mt = 0; mt < 4; ++mt)
#pragma unroll
      for (int jt = 0; jt < 2; ++jt)
        accO[mt][jt] = MFMA32(av[mt], pb[jt], accO[mt][jt]);
  }

  __syncthreads();
#pragma unroll
  for (int mt = 0; mt < 4; ++mt)
#pragma unroll
    for (int jt = 0; jt < 2; ++jt)
#pragma unroll
      for (int r = 0; r < 4; ++r)
        sO[(wv * 32 + jt * 16 + l16) * 72 + mt * 16 + 4 * g + r] =
            (_Float16)(accO[mt][jt][r] * rinv[jt]);
  __syncthreads();

  const int hh = tid >> 1, d0 = (tid & 1) * 32;
  const _Float16* s = sO + hh * 72 + d0;
  _Float16* dst = attnout + ((long)bl * 16384 + hh * 128 + w) * 256 + head * 64 + d0;
#pragma unroll
  for (int e = 0; e < 4; ++e)
    *(u4*)(dst + e * 8) = *(const u4*)(s + e * 8);
}

// ---------------- K3: out[b][co][t] = Wproj^T[co][c]*attnout[t][c]+bproj --------
__global__ __launch_bounds__(256, 4) void k3_proj(const _Float16* __restrict__ attnout,
                                                  const _Float16* __restrict__ wpt,
                                                  const float* __restrict__ bproj,
                                                  float* __restrict__ out,
                                                  int b_base, int nb) {
  const int ct = blockIdx.x, tt = blockIdx.y, bl = blockIdx.z;
  const int b = b_base + bl;
  const int tid = threadIdx.x;
  const int lane = tid & 63, wv = tid >> 6;
  const int g = lane >> 4, l16 = lane & 15;
  const int wr = wv >> 1, wc = wv & 1;
  const int co0 = ct * 128;
  const long t0 = (long)tt * 128;

  __shared__ __align__(16) char smem[33792];
  _Float16* sA = (_Float16*)smem;   // [128 co][64]
  _Float16* sB = sA + 128 * 64;     // [128 t][64]
  float* sOut = (float*)smem;       // reuse: [64][132] f32

  f4 acc[4][4];
#pragma unroll
  for (int mt = 0; mt < 4; ++mt)
#pragma unroll
    for (int nt = 0; nt < 4; ++nt)
#pragma unroll
      for (int r = 0; r < 4; ++r) acc[mt][nt][r] = 0.f;

  const _Float16* Ab = wpt + (long)co0 * 256;
  const _Float16* Bb = attnout + ((long)bl * 16384 + t0) * 256;
  const int r0 = wv * 32;
  const int rl = lane >> 3, ch = (lane & 7) * 8;

  for (int kc = 0; kc < 4; ++kc) {
    const int c0 = kc * 64;
#pragma unroll
    for (int i = 0; i < 4; ++i) {
      const int row = r0 + i * 8 + rl;
      gll16(Ab + (long)row * 256 + c0 + ch, sA + (r0 + i * 8) * 64);
      gll16(Bb + (long)row * 256 + c0 + ch, sB + (r0 + i * 8) * 64);
    }
    __syncthreads();
#pragma unroll
    for (int ks = 0; ks < 2; ++ks) {
      const int k = ks * 32 + 8 * g;
      h8 af[4], bf[4];
#pragma unroll
      for (int mt = 0; mt < 4; ++mt)
        af[mt] = *(const h8*)(sA + (wr * 64 + mt * 16 + l16) * 64 + k);
#pragma unroll
      for (int nt = 0; nt < 4; ++nt)
        bf[nt] = *(const h8*)(sB + (wc * 64 + nt * 16 + l16) * 64 + k);
#pragma unroll
      for (int mt = 0; mt < 4; ++mt)
#pragma unroll
        for (int nt = 0; nt < 4; ++nt)
          acc[mt][nt] = MFMA32(af[mt], bf[nt], acc[mt][nt]);
    }
    __syncthreads();
  }

#pragma unroll
  for (int h2 = 0; h2 < 2; ++h2) {
    if (h2) __syncthreads();
    if (wr == h2) {
#pragma unroll
      for (int mt = 0; mt < 4; ++mt) {
        f4 bb = *(const f4*)(bproj + co0 + h2 * 64 + mt * 16 + 4 * g);
#pragma unroll
        for (int nt = 0; nt < 4; ++nt)
#pragma unroll
          for (int r = 0; r < 4; ++r)
            sOut[(mt * 16 + 4 * g + r) * 132 + wc * 64 + nt * 16 + l16] =
                acc[mt][nt][r] + bb[r];
      }
    }
    __syncthreads();
    const int row = tid >> 2, seg = (tid & 3) * 32;
    const float* s = sOut + row * 132 + seg;
    float* dst = out + ((long)b * 256 + co0 + h2 * 64 + row) * 16384 + t0 + seg;
#pragma unroll
    for (int e = 0; e < 8; ++e)
      *(f4*)(dst + e * 4) = *(const f4*)(s + e * 4);
  }
}

// ---------------- launch ----------------
extern "C" void kernel_launch(void* const* d_in, const int* in_sizes, int n_in,
                              void* d_out, int out_size, void* d_ws, size_t ws_size,
                              hipStream_t stream) {
  const float* x = (const float*)d_in[0];
  const float* Wqkv = (const float*)d_in[1];
  const float* bqkv = (const float*)d_in[2];
  const float* Wproj = (const float*)d_in[3];
  const float* bproj = (const float*)d_in[4];
  float* out = (float*)d_out;

  char* ws = (char*)d_ws;
  // Layout: [wqt 384K][wpt 128K][qkv nb*24Mi][shared nb*8Mi (xt, then attnout)]
  const long WQT = 393216L, WPT = 131072L;
  const long PER_B = 25165824L + 8388608L;
  long nb_l = ((long)ws_size - (WQT + WPT)) / PER_B;
  // Cap nb at 2: per-pass intermediates (128MB) stay L3-resident. (v9 at nb=8:
  // 512MB working set thrashed the 256MB L3 -> k1 wrote 197MB to HBM @2.2TB/s.)
  int nb = nb_l < 1 ? 1 : (nb_l > 2 ? 2 : (int)nb_l);

  _Float16* wqt = (_Float16*)ws;
  _Float16* wpt = (_Float16*)(ws + WQT);
  _Float16* qkv = (_Float16*)(ws + WQT + WPT);
  _Float16* shared = (_Float16*)(ws + WQT + WPT + (long)nb * 25165824L);
  _Float16* xt = shared;       // live: prep_x -> k1
  _Float16* attnout = shared;  // live: k2 -> k3 (after xt dead)

  prep_w<<<1024, 256, 0, stream>>>(Wqkv, Wproj, wqt, wpt);

  for (int b0 = 0; b0 < 8; b0 += nb) {
    int nbv = (8 - b0 < nb) ? (8 - b0) : nb;
    prep_x<<<dim3(128, nbv), 256, 0, stream>>>(x, xt, b0);
    k1_qkv<<<768 * nbv, 256, 0, stream>>>(xt, wqt, bqkv, qkv, nbv);
    k2_attn<<<dim3(128, 4, nbv), 256, 0, stream>>>(qkv, attnout, nbv);
    k3_proj<<<dim3(2, 128, nbv), 256, 0, stream>>>(attnout, wpt, bproj, out, b0, nbv);
  }
}

// Round 11
// 267.641 us; speedup vs baseline: 1.1879x; 1.1879x over previous
//
#include <hip/hip_runtime.h>

// AxisAttention: x(8,256,128,128) -> per (b,w) sequence over h: QKV GEMM, 4-head
// attention (S=128, d=64), proj GEMM, transposed fp32 output.
// All matmuls: v_mfma_f32_16x16x32_f16, fp32 accum.
// v11: nb=8 reverted (v10's nb=2 chunking regressed: launch serialization).
//      prep_x FUSED into k1f: block = (b, h, w-half) covers ALL 768f x 64t, so
//      each x element is transposed exactly once (v6's per-ft redo avoided).
//      xt buffer eliminated (-512MB traffic). B-fragments preloaded to 64 VGPRs
//      once, reused across 6 ft; A staged per (ft,kc) via gload_lds (v9 pattern).
//      k2/k3/prep_w byte-identical to v9.

typedef _Float16 h4 __attribute__((ext_vector_type(4)));
typedef _Float16 h8 __attribute__((ext_vector_type(8)));
typedef float f4 __attribute__((ext_vector_type(4)));
typedef unsigned int u4 __attribute__((ext_vector_type(4)));

#define MFMA32(a, b, c) __builtin_amdgcn_mfma_f32_16x16x32_f16((a), (b), (c), 0, 0, 0)

__device__ __forceinline__ void gll16(const _Float16* g, _Float16* l) {
  __builtin_amdgcn_global_load_lds(
      (const __attribute__((address_space(1))) void*)g,
      (__attribute__((address_space(3))) void*)l, 16, 0, 0);
}

// ---------------- prep: W^T fp16 (wqt[f][c], wpt[f][c]) ----------------
__global__ __launch_bounds__(256) void prep_w(const float* __restrict__ Wqkv,
                                              const float* __restrict__ Wproj,
                                              _Float16* __restrict__ wqt,
                                              _Float16* __restrict__ wpt) {
  int i = blockIdx.x * 256 + threadIdx.x;  // 196608 + 65536
  if (i < 768 * 256) {
    int f = i >> 8, c = i & 255;
    wqt[i] = (_Float16)Wqkv[c * 768 + f];
  } else {
    int j = i - 768 * 256;
    int f = j >> 8, c = j & 255;
    wpt[j] = (_Float16)Wproj[c * 256 + f];
  }
}

// ---------------- K1F: fused x-transpose + QKV GEMM ----------------
// Block (bl, hb, wh): tokens t = (w0..w0+63) at fixed h=hb; computes all 768 f.
// xT[64t][264c] fp16 built once from coalesced x reads; B-frags preloaded to
// registers; per (ft,kc) only A (wqt 16KB) staged via gload_lds.
// qkv layout: [qi*nb+bl][head][w][h*64+d]  (identical to v9; k2 unchanged)
__global__ __launch_bounds__(256, 2) void k1f(const float* __restrict__ x,
                                              const _Float16* __restrict__ wqt,
                                              const float* __restrict__ bqkv,
                                              _Float16* __restrict__ qkv,
                                              int b_base, int nb) {
  const int wg = blockIdx.x;
  const int xcd = wg & 7, seq = wg >> 3;
  const int id = xcd * (nb * 32) + seq;  // bijective: grid = nb*256, %8 == 0
  const int hb = id & 127;
  const int rest = id >> 7;
  const int wh = rest & 1, bl = rest >> 1;
  const int b = b_base + bl;
  const int w0 = wh * 64;

  const int tid = threadIdx.x;
  const int lane = tid & 63, wv = tid >> 6;
  const int g = lane >> 4, l16 = lane & 15;
  const int wr = wv >> 1, wc = wv & 1;  // wave -> (f-half of 128, t-half of 64)

  __shared__ __align__(16) char smem[67584];
  _Float16* sA = (_Float16*)smem;        // [128 f][64 c]   16384 B
  _Float16* sXT = sA + 128 * 64;         // [64 t][264 c]   33792 B
  _Float16* sO = sXT + 64 * 264;         // [64 t][136 f]   17408 B

  // ---- phase 0: transpose x[b][c][hb][w0..w0+63] -> sXT[w][c] (fp16) ----
  {
    const int r4 = tid >> 2, j0 = tid & 3;
#pragma unroll
    for (int p = 0; p < 4; ++p) {
      const int c = p * 64 + r4;
      const float* src = x + (((long)b * 256 + c) * 128 + hb) * 128 + w0;
      f4 v[4];
#pragma unroll
      for (int k = 0; k < 4; ++k) v[k] = *(const f4*)(src + (j0 + 4 * k) * 4);
#pragma unroll
      for (int k = 0; k < 4; ++k)
#pragma unroll
        for (int i = 0; i < 4; ++i)
          sXT[((j0 + 4 * k) * 4 + i) * 264 + c] = (_Float16)v[k][i];
    }
  }
  __syncthreads();

  // ---- phase 1: preload ALL B-fragments (whole K=256) into registers ----
  h8 bfr[4][2][2];  // [kc][ks][nt]
#pragma unroll
  for (int kc = 0; kc < 4; ++kc)
#pragma unroll
    for (int ks = 0; ks < 2; ++ks)
#pragma unroll
      for (int nt = 0; nt < 2; ++nt) {
        const int t = wc * 32 + nt * 16 + l16;
        bfr[kc][ks][nt] =
            *(const h8*)(sXT + t * 264 + kc * 64 + ks * 32 + 8 * g);
      }

  const int r0 = wv * 32;
  const int rl = lane >> 3, ch = (lane & 7) * 8;
  const int wl = tid >> 2, dc = tid & 3;

  // ---- main loop over 6 f-tiles of 128 ----
  for (int ft = 0; ft < 6; ++ft) {
    const int f0 = ft * 128;
    f4 acc[4][2];
#pragma unroll
    for (int mt = 0; mt < 4; ++mt)
#pragma unroll
      for (int nt = 0; nt < 2; ++nt)
#pragma unroll
        for (int r = 0; r < 4; ++r) acc[mt][nt][r] = 0.f;

    for (int kc = 0; kc < 4; ++kc) {
      // stage A tile [128 f][64 c] (v9-proven gload_lds pattern)
#pragma unroll
      for (int i = 0; i < 4; ++i) {
        const int row = r0 + i * 8 + rl;
        gll16(wqt + (long)(f0 + row) * 256 + kc * 64 + ch, sA + (r0 + i * 8) * 64);
      }
      __syncthreads();
#pragma unroll
      for (int ks = 0; ks < 2; ++ks) {
        h8 af[4];
#pragma unroll
        for (int mt = 0; mt < 4; ++mt)
          af[mt] = *(const h8*)(sA + (wr * 64 + mt * 16 + l16) * 64 + ks * 32 + 8 * g);
#pragma unroll
        for (int mt = 0; mt < 4; ++mt)
#pragma unroll
          for (int nt = 0; nt < 2; ++nt)
            acc[mt][nt] = MFMA32(af[mt], bfr[kc][ks][nt], acc[mt][nt]);
      }
      __syncthreads();
    }

    // epilogue: bias + repack to sO[t][f-local], then coalesced qkv store
#pragma unroll
    for (int mt = 0; mt < 4; ++mt) {
      f4 bb = *(const f4*)(bqkv + f0 + wr * 64 + mt * 16 + 4 * g);
#pragma unroll
      for (int nt = 0; nt < 2; ++nt) {
        const int tl = wc * 32 + nt * 16 + l16;
#pragma unroll
        for (int r = 0; r < 4; ++r)
          sO[tl * 136 + wr * 64 + mt * 16 + 4 * g + r] =
              (_Float16)(acc[mt][nt][r] + bb[r]);
      }
    }
    __syncthreads();
#pragma unroll
    for (int h2 = 0; h2 < 2; ++h2) {
      const int fh = f0 + h2 * 64;
      const int qi = fh >> 8, head = (fh >> 6) & 3;
      _Float16* dst = qkv + (((long)(qi * nb + bl) * 4 + head) * 128 + w0 + wl) * 8192 +
                      hb * 64 + dc * 16;
      const _Float16* s = sO + wl * 136 + h2 * 64 + dc * 16;
      *(u4*)dst = *(const u4*)s;
      *(u4*)(dst + 8) = *(const u4*)(s + 8);
    }
    __syncthreads();
  }
}

// ---------------- K2: attention per (w, head, bl) ---------------- (v9-proven)
__global__ __launch_bounds__(256) void k2_attn(const _Float16* __restrict__ qkv,
                                               _Float16* __restrict__ attnout,
                                               int nb) {
  const int w = blockIdx.x, head = blockIdx.y, bl = blockIdx.z;
  const int tid = threadIdx.x;
  const int lane = tid & 63, wv = tid >> 6;
  const int g = lane >> 4, l16 = lane & 15;

  __shared__ __align__(16) char smem[(128 * 72 * 2 + 64 * 136) * 2];  // 54272 B
  _Float16* sQ = (_Float16*)smem;
  _Float16* sK = sQ + 128 * 72;
  _Float16* sVT = sK + 128 * 72;
  _Float16* sP = sQ;
  _Float16* sO = sQ;

  const long base = (((long)bl * 4 + head) * 128 + w) * 8192;
  const long QS = (long)nb * 4 * 128 * 8192;
  const _Float16* qg = qkv + base;
  const _Float16* kg = qkv + base + QS;
  const _Float16* vg = qkv + base + 2 * QS;

#pragma unroll
  for (int i = 0; i < 4; ++i) {
    int u = tid + 256 * i;
    int hh = u >> 3, dq = u & 7;
    *(u4*)(sQ + hh * 72 + dq * 8) = *(const u4*)(qg + hh * 64 + dq * 8);
    *(u4*)(sK + hh * 72 + dq * 8) = *(const u4*)(kg + hh * 64 + dq * 8);
  }
  {
    const int hh = tid & 127, dcv = tid >> 7;
#pragma unroll
    for (int jj = 0; jj < 4; ++jj) {
      u4 vv = *(const u4*)(vg + hh * 64 + dcv * 32 + jj * 8);
      const _Float16* pe = (const _Float16*)&vv;
#pragma unroll
      for (int e = 0; e < 8; ++e)
        sVT[(dcv * 32 + jj * 8 + e) * 136 + hh] = pe[e];
    }
  }
  __syncthreads();

  f4 accS[8][2];
  for (int i = 0; i < 8; ++i)
    for (int jt = 0; jt < 2; ++jt)
      for (int r = 0; r < 4; ++r) accS[i][jt][r] = 0.f;
#pragma unroll
  for (int ks = 0; ks < 2; ++ks) {
    const int k = ks * 32 + 8 * g;
    h8 af[8], bf[2];
#pragma unroll
    for (int i = 0; i < 8; ++i)
      af[i] = *(const h8*)(sK + (i * 16 + l16) * 72 + k);
#pragma unroll
    for (int jt = 0; jt < 2; ++jt)
      bf[jt] = *(const h8*)(sQ + (wv * 32 + jt * 16 + l16) * 72 + k);
#pragma unroll
    for (int i = 0; i < 8; ++i)
#pragma unroll
      for (int jt = 0; jt < 2; ++jt)
        accS[i][jt] = MFMA32(af[i], bf[jt], accS[i][jt]);
  }

  float rinv[2];
#pragma unroll
  for (int jt = 0; jt < 2; ++jt) {
    float m = -1e30f;
    for (int i = 0; i < 8; ++i)
      for (int r = 0; r < 4; ++r) m = fmaxf(m, accS[i][jt][r]);
    m = fmaxf(m, __shfl_xor(m, 16));
    m = fmaxf(m, __shfl_xor(m, 32));
    float s = 0.f;
    for (int i = 0; i < 8; ++i)
      for (int r = 0; r < 4; ++r) {
        float p = __expf((accS[i][jt][r] - m) * 0.125f);
        accS[i][jt][r] = p;
        s += p;
      }
    s += __shfl_xor(s, 16);
    s += __shfl_xor(s, 32);
    rinv[jt] = 1.0f / s;
  }

  __syncthreads();
#pragma unroll
  for (int jt = 0; jt < 2; ++jt) {
    const int hq = wv * 32 + jt * 16 + l16;
#pragma unroll
    for (int i = 0; i < 8; ++i) {
      h4 pv;
      pv[0] = (_Float16)accS[i][jt][0];
      pv[1] = (_Float16)accS[i][jt][1];
      pv[2] = (_Float16)accS[i][jt][2];
      pv[3] = (_Float16)accS[i][jt][3];
      *(h4*)(sP + hq * 136 + i * 16 + 4 * g) = pv;
    }
  }
  __syncthreads();

  f4 accO[4][2];
  for (int mt = 0; mt < 4; ++mt)
    for (int jt = 0; jt < 2; ++jt)
      for (int r = 0; r < 4; ++r) accO[mt][jt][r] = 0.f;
#pragma unroll
  for (int i2 = 0; i2 < 4; ++i2) {
    const int k = i2 * 32 + 8 * g;
    h8 av[4], pb[2];
#pragma unroll
    for (int mt = 0; mt < 4; ++mt)
      av[mt] = *(const h8*)(sVT + (mt * 16 + l16) * 136 + k);
#pragma unroll
    for (int jt = 0; jt < 2; ++jt)
      pb[jt] = *(const h8*)(sP + (wv * 32 + jt * 16 + l16) * 136 + k);
#pragma unroll
    for (int mt = 0; mt < 4; ++mt)
#pragma unroll
      for (int jt = 0; jt < 2; ++jt)
        accO[mt][jt] = MFMA32(av[mt], pb[jt], accO[mt][jt]);
  }

  __syncthreads();
#pragma unroll
  for (int mt = 0; mt < 4; ++mt)
#pragma unroll
    for (int jt = 0; jt < 2; ++jt)
#pragma unroll
      for (int r = 0; r < 4; ++r)
        sO[(wv * 32 + jt * 16 + l16) * 72 + mt * 16 + 4 * g + r] =
            (_Float16)(accO[mt][jt][r] * rinv[jt]);
  __syncthreads();

  const int hh = tid >> 1, d0 = (tid & 1) * 32;
  const _Float16* s = sO + hh * 72 + d0;
  _Float16* dst = attnout + ((long)bl * 16384 + hh * 128 + w) * 256 + head * 64 + d0;
#pragma unroll
  for (int e = 0; e < 4; ++e)
    *(u4*)(dst + e * 8) = *(const u4*)(s + e * 8);
}

// ---------------- K3: out[b][co][t] = Wproj^T[co][c]*attnout[t][c]+bproj --------
// (v9-proven)
__global__ __launch_bounds__(256, 4) void k3_proj(const _Float16* __restrict__ attnout,
                                                  const _Float16* __restrict__ wpt,
                                                  const float* __restrict__ bproj,
                                                  float* __restrict__ out,
                                                  int b_base, int nb) {
  const int ct = blockIdx.x, tt = blockIdx.y, bl = blockIdx.z;
  const int b = b_base + bl;
  const int tid = threadIdx.x;
  const int lane = tid & 63, wv = tid >> 6;
  const int g = lane >> 4, l16 = lane & 15;
  const int wr = wv >> 1, wc = wv & 1;
  const int co0 = ct * 128;
  const long t0 = (long)tt * 128;

  __shared__ __align__(16) char smem[33792];
  _Float16* sA = (_Float16*)smem;   // [128 co][64]
  _Float16* sB = sA + 128 * 64;     // [128 t][64]
  float* sOut = (float*)smem;       // reuse: [64][132] f32

  f4 acc[4][4];
#pragma unroll
  for (int mt = 0; mt < 4; ++mt)
#pragma unroll
    for (int nt = 0; nt < 4; ++nt)
#pragma unroll
      for (int r = 0; r < 4; ++r) acc[mt][nt][r] = 0.f;

  const _Float16* Ab = wpt + (long)co0 * 256;
  const _Float16* Bb = attnout + ((long)bl * 16384 + t0) * 256;
  const int r0 = wv * 32;
  const int rl = lane >> 3, ch = (lane & 7) * 8;

  for (int kc = 0; kc < 4; ++kc) {
    const int c0 = kc * 64;
#pragma unroll
    for (int i = 0; i < 4; ++i) {
      const int row = r0 + i * 8 + rl;
      gll16(Ab + (long)row * 256 + c0 + ch, sA + (r0 + i * 8) * 64);
      gll16(Bb + (long)row * 256 + c0 + ch, sB + (r0 + i * 8) * 64);
    }
    __syncthreads();
#pragma unroll
    for (int ks = 0; ks < 2; ++ks) {
      const int k = ks * 32 + 8 * g;
      h8 af[4], bf[4];
#pragma unroll
      for (int mt = 0; mt < 4; ++mt)
        af[mt] = *(const h8*)(sA + (wr * 64 + mt * 16 + l16) * 64 + k);
#pragma unroll
      for (int nt = 0; nt < 4; ++nt)
        bf[nt] = *(const h8*)(sB + (wc * 64 + nt * 16 + l16) * 64 + k);
#pragma unroll
      for (int mt = 0; mt < 4; ++mt)
#pragma unroll
        for (int nt = 0; nt < 4; ++nt)
          acc[mt][nt] = MFMA32(af[mt], bf[nt], acc[mt][nt]);
    }
    __syncthreads();
  }

#pragma unroll
  for (int h2 = 0; h2 < 2; ++h2) {
    if (h2) __syncthreads();
    if (wr == h2) {
#pragma unroll
      for (int mt = 0; mt < 4; ++mt) {
        f4 bb = *(const f4*)(bproj + co0 + h2 * 64 + mt * 16 + 4 * g);
#pragma unroll
        for (int nt = 0; nt < 4; ++nt)
#pragma unroll
          for (int r = 0; r < 4; ++r)
            sOut[(mt * 16 + 4 * g + r) * 132 + wc * 64 + nt * 16 + l16] =
                acc[mt][nt][r] + bb[r];
      }
    }
    __syncthreads();
    const int row = tid >> 2, seg = (tid & 3) * 32;
    const float* s = sOut + row * 132 + seg;
    float* dst = out + ((long)b * 256 + co0 + h2 * 64 + row) * 16384 + t0 + seg;
#pragma unroll
    for (int e = 0; e < 8; ++e)
      *(f4*)(dst + e * 4) = *(const f4*)(s + e * 4);
  }
}

// ---------------- launch ----------------
extern "C" void kernel_launch(void* const* d_in, const int* in_sizes, int n_in,
                              void* d_out, int out_size, void* d_ws, size_t ws_size,
                              hipStream_t stream) {
  const float* x = (const float*)d_in[0];
  const float* Wqkv = (const float*)d_in[1];
  const float* bqkv = (const float*)d_in[2];
  const float* Wproj = (const float*)d_in[3];
  const float* bproj = (const float*)d_in[4];
  float* out = (float*)d_out;

  char* ws = (char*)d_ws;
  // Layout: [wqt 384K][wpt 128K][qkv nb*24Mi][attnout nb*8Mi]
  const long WQT = 393216L, WPT = 131072L;
  const long PER_B = 25165824L + 8388608L;
  long nb_l = ((long)ws_size - (WQT + WPT)) / PER_B;
  int nb = nb_l < 1 ? 1 : (nb_l > 8 ? 8 : (int)nb_l);

  _Float16* wqt = (_Float16*)ws;
  _Float16* wpt = (_Float16*)(ws + WQT);
  _Float16* qkv = (_Float16*)(ws + WQT + WPT);
  _Float16* attnout = (_Float16*)(ws + WQT + WPT + (long)nb * 25165824L);

  prep_w<<<1024, 256, 0, stream>>>(Wqkv, Wproj, wqt, wpt);

  for (int b0 = 0; b0 < 8; b0 += nb) {
    int nbv = (8 - b0 < nb) ? (8 - b0) : nb;
    k1f<<<nbv * 256, 256, 0, stream>>>(x, wqt, bqkv, qkv, b0, nbv);
    k2_attn<<<dim3(128, 4, nbv), 256, 0, stream>>>(qkv, attnout, nbv);
    k3_proj<<<dim3(2, 128, nbv), 256, 0, stream>>>(attnout, wpt, bproj, out, b0, nbv);
  }
}

// Round 12
// 249.545 us; speedup vs baseline: 1.2741x; 1.0725x over previous
//
#include <hip/hip_runtime.h>

// AxisAttention: x(8,256,128,128) -> per (b,w) sequence over h: QKV GEMM, 4-head
// attention (S=128, d=64), proj GEMM, transposed fp32 output.
// All matmuls: v_mfma_f32_16x16x32_f16, fp32 accum.
// v12 = v11 with k1f fixed:
//  - LDS 67.5KB -> 34KB: sXT (x-transpose tile) is DEAD after B-frags are
//    preloaded to registers; sA/sO now alias it. launch_bounds(256,4):
//    occupancy 2 -> 4 blocks/CU.
//  - phase-0 x reads remapped to 128B-coalesced (8 lanes x 16B contiguous).
// k2/k3/prep_w byte-identical to v11 (v9-proven).

typedef _Float16 h4 __attribute__((ext_vector_type(4)));
typedef _Float16 h8 __attribute__((ext_vector_type(8)));
typedef float f4 __attribute__((ext_vector_type(4)));
typedef unsigned int u4 __attribute__((ext_vector_type(4)));

#define MFMA32(a, b, c) __builtin_amdgcn_mfma_f32_16x16x32_f16((a), (b), (c), 0, 0, 0)

__device__ __forceinline__ void gll16(const _Float16* g, _Float16* l) {
  __builtin_amdgcn_global_load_lds(
      (const __attribute__((address_space(1))) void*)g,
      (__attribute__((address_space(3))) void*)l, 16, 0, 0);
}

// ---------------- prep: W^T fp16 (wqt[f][c], wpt[f][c]) ----------------
__global__ __launch_bounds__(256) void prep_w(const float* __restrict__ Wqkv,
                                              const float* __restrict__ Wproj,
                                              _Float16* __restrict__ wqt,
                                              _Float16* __restrict__ wpt) {
  int i = blockIdx.x * 256 + threadIdx.x;  // 196608 + 65536
  if (i < 768 * 256) {
    int f = i >> 8, c = i & 255;
    wqt[i] = (_Float16)Wqkv[c * 768 + f];
  } else {
    int j = i - 768 * 256;
    int f = j >> 8, c = j & 255;
    wpt[j] = (_Float16)Wproj[c * 256 + f];
  }
}

// ---------------- K1F: fused x-transpose + QKV GEMM ----------------
// Block (bl, hb, wh): tokens t = (w0..w0+63) at fixed h=hb; computes all 768 f.
// Phase 0: coalesced 128B x reads -> sXT[64t][264c] fp16.
// Phase 1: preload ALL B-fragments (K=256) into 64 VGPRs; sXT dead after.
// Main: per (ft,kc) stage A (wqt, L2-resident) via gload_lds; 16 MFMA/wave/kc.
// qkv layout: [qi*nb+bl][head][w][h*64+d]  (k2-ready, 16KB contiguous chunks)
__global__ __launch_bounds__(256, 4) void k1f(const float* __restrict__ x,
                                              const _Float16* __restrict__ wqt,
                                              const float* __restrict__ bqkv,
                                              _Float16* __restrict__ qkv,
                                              int b_base, int nb) {
  const int wg = blockIdx.x;
  const int xcd = wg & 7, seq = wg >> 3;
  const int id = xcd * (nb * 32) + seq;  // bijective: grid = nb*256, %8 == 0
  const int hb = id & 127;
  const int rest = id >> 7;
  const int wh = rest & 1, bl = rest >> 1;
  const int b = b_base + bl;
  const int w0 = wh * 64;

  const int tid = threadIdx.x;
  const int lane = tid & 63, wv = tid >> 6;
  const int g = lane >> 4, l16 = lane & 15;
  const int wr = wv >> 1, wc = wv & 1;  // wave -> (f-half of 128, t-half of 64)

  __shared__ __align__(16) char smem[34816];
  _Float16* sXT = (_Float16*)smem;         // [64 t][264 c] 33792 B (phase 0-1 ONLY)
  _Float16* sA = (_Float16*)smem;          // [128 f][64 c] 16384 B (aliases sXT)
  _Float16* sO = (_Float16*)(smem + 16384);  // [64 t][136 f] 17408 B (aliases sXT)

  // ---- phase 0: transpose x[b][c][hb][w0..w0+63] -> sXT[w][c] (fp16) ----
  {
    const int j0 = tid & 7, r8 = tid >> 3;  // 8 lanes x 16B = 128B coalesced
#pragma unroll
    for (int p = 0; p < 8; ++p) {
      const int c = p * 32 + r8;
      const float* src = x + (((long)b * 256 + c) * 128 + hb) * 128 + w0;
      f4 v0 = *(const f4*)(src + j0 * 4);
      f4 v1 = *(const f4*)(src + (j0 + 8) * 4);
#pragma unroll
      for (int i = 0; i < 4; ++i) {
        sXT[(j0 * 4 + i) * 264 + c] = (_Float16)v0[i];
        sXT[((j0 + 8) * 4 + i) * 264 + c] = (_Float16)v1[i];
      }
    }
  }
  __syncthreads();

  // ---- phase 1: preload ALL B-fragments (whole K=256) into registers ----
  h8 bfr[4][2][2];  // [kc][ks][nt]
#pragma unroll
  for (int kc = 0; kc < 4; ++kc)
#pragma unroll
    for (int ks = 0; ks < 2; ++ks)
#pragma unroll
      for (int nt = 0; nt < 2; ++nt) {
        const int t = wc * 32 + nt * 16 + l16;
        bfr[kc][ks][nt] =
            *(const h8*)(sXT + t * 264 + kc * 64 + ks * 32 + 8 * g);
      }
  __syncthreads();  // sXT dead; sA/sO may now overwrite it

  const int r0 = wv * 32;
  const int rl = lane >> 3, ch = (lane & 7) * 8;
  const int wl = tid >> 2, dc = tid & 3;

  // ---- main loop over 6 f-tiles of 128 ----
  for (int ft = 0; ft < 6; ++ft) {
    const int f0 = ft * 128;
    f4 acc[4][2];
#pragma unroll
    for (int mt = 0; mt < 4; ++mt)
#pragma unroll
      for (int nt = 0; nt < 2; ++nt)
#pragma unroll
        for (int r = 0; r < 4; ++r) acc[mt][nt][r] = 0.f;

    for (int kc = 0; kc < 4; ++kc) {
      // stage A tile [128 f][64 c] via gload_lds (wqt is L2-resident)
#pragma unroll
      for (int i = 0; i < 4; ++i) {
        const int row = r0 + i * 8 + rl;
        gll16(wqt + (long)(f0 + row) * 256 + kc * 64 + ch, sA + (r0 + i * 8) * 64);
      }
      __syncthreads();
#pragma unroll
      for (int ks = 0; ks < 2; ++ks) {
        h8 af[4];
#pragma unroll
        for (int mt = 0; mt < 4; ++mt)
          af[mt] = *(const h8*)(sA + (wr * 64 + mt * 16 + l16) * 64 + ks * 32 + 8 * g);
#pragma unroll
        for (int mt = 0; mt < 4; ++mt)
#pragma unroll
          for (int nt = 0; nt < 2; ++nt)
            acc[mt][nt] = MFMA32(af[mt], bfr[kc][ks][nt], acc[mt][nt]);
      }
      __syncthreads();
    }

    // epilogue: bias + repack to sO[t][f-local] (sO disjoint from sA)
#pragma unroll
    for (int mt = 0; mt < 4; ++mt) {
      f4 bb = *(const f4*)(bqkv + f0 + wr * 64 + mt * 16 + 4 * g);
#pragma unroll
      for (int nt = 0; nt < 2; ++nt) {
        const int tl = wc * 32 + nt * 16 + l16;
#pragma unroll
        for (int r = 0; r < 4; ++r)
          sO[tl * 136 + wr * 64 + mt * 16 + 4 * g + r] =
              (_Float16)(acc[mt][nt][r] + bb[r]);
      }
    }
    __syncthreads();
#pragma unroll
    for (int h2 = 0; h2 < 2; ++h2) {
      const int fh = f0 + h2 * 64;
      const int qi = fh >> 8, head = (fh >> 6) & 3;
      _Float16* dst = qkv + (((long)(qi * nb + bl) * 4 + head) * 128 + w0 + wl) * 8192 +
                      hb * 64 + dc * 16;
      const _Float16* s = sO + wl * 136 + h2 * 64 + dc * 16;
      *(u4*)dst = *(const u4*)s;
      *(u4*)(dst + 8) = *(const u4*)(s + 8);
    }
    __syncthreads();
  }
}

// ---------------- K2: attention per (w, head, bl) ---------------- (v9-proven)
__global__ __launch_bounds__(256) void k2_attn(const _Float16* __restrict__ qkv,
                                               _Float16* __restrict__ attnout,
                                               int nb) {
  const int w = blockIdx.x, head = blockIdx.y, bl = blockIdx.z;
  const int tid = threadIdx.x;
  const int lane = tid & 63, wv = tid >> 6;
  const int g = lane >> 4, l16 = lane & 15;

  __shared__ __align__(16) char smem[(128 * 72 * 2 + 64 * 136) * 2];  // 54272 B
  _Float16* sQ = (_Float16*)smem;
  _Float16* sK = sQ + 128 * 72;
  _Float16* sVT = sK + 128 * 72;
  _Float16* sP = sQ;
  _Float16* sO = sQ;

  const long base = (((long)bl * 4 + head) * 128 + w) * 8192;
  const long QS = (long)nb * 4 * 128 * 8192;
  const _Float16* qg = qkv + base;
  const _Float16* kg = qkv + base + QS;
  const _Float16* vg = qkv + base + 2 * QS;

#pragma unroll
  for (int i = 0; i < 4; ++i) {
    int u = tid + 256 * i;
    int hh = u >> 3, dq = u & 7;
    *(u4*)(sQ + hh * 72 + dq * 8) = *(const u4*)(qg + hh * 64 + dq * 8);
    *(u4*)(sK + hh * 72 + dq * 8) = *(const u4*)(kg + hh * 64 + dq * 8);
  }
  {
    const int hh = tid & 127, dcv = tid >> 7;
#pragma unroll
    for (int jj = 0; jj < 4; ++jj) {
      u4 vv = *(const u4*)(vg + hh * 64 + dcv * 32 + jj * 8);
      const _Float16* pe = (const _Float16*)&vv;
#pragma unroll
      for (int e = 0; e < 8; ++e)
        sVT[(dcv * 32 + jj * 8 + e) * 136 + hh] = pe[e];
    }
  }
  __syncthreads();

  f4 accS[8][2];
  for (int i = 0; i < 8; ++i)
    for (int jt = 0; jt < 2; ++jt)
      for (int r = 0; r < 4; ++r) accS[i][jt][r] = 0.f;
#pragma unroll
  for (int ks = 0; ks < 2; ++ks) {
    const int k = ks * 32 + 8 * g;
    h8 af[8], bf[2];
#pragma unroll
    for (int i = 0; i < 8; ++i)
      af[i] = *(const h8*)(sK + (i * 16 + l16) * 72 + k);
#pragma unroll
    for (int jt = 0; jt < 2; ++jt)
      bf[jt] = *(const h8*)(sQ + (wv * 32 + jt * 16 + l16) * 72 + k);
#pragma unroll
    for (int i = 0; i < 8; ++i)
#pragma unroll
      for (int jt = 0; jt < 2; ++jt)
        accS[i][jt] = MFMA32(af[i], bf[jt], accS[i][jt]);
  }

  float rinv[2];
#pragma unroll
  for (int jt = 0; jt < 2; ++jt) {
    float m = -1e30f;
    for (int i = 0; i < 8; ++i)
      for (int r = 0; r < 4; ++r) m = fmaxf(m, accS[i][jt][r]);
    m = fmaxf(m, __shfl_xor(m, 16));
    m = fmaxf(m, __shfl_xor(m, 32));
    float s = 0.f;
    for (int i = 0; i < 8; ++i)
      for (int r = 0; r < 4; ++r) {
        float p = __expf((accS[i][jt][r] - m) * 0.125f);
        accS[i][jt][r] = p;
        s += p;
      }
    s += __shfl_xor(s, 16);
    s += __shfl_xor(s, 32);
    rinv[jt] = 1.0f / s;
  }

  __syncthreads();
#pragma unroll
  for (int jt = 0; jt < 2; ++jt) {
    const int hq = wv * 32 + jt * 16 + l16;
#pragma unroll
    for (int i = 0; i < 8; ++i) {
      h4 pv;
      pv[0] = (_Float16)accS[i][jt][0];
      pv[1] = (_Float16)accS[i][jt][1];
      pv[2] = (_Float16)accS[i][jt][2];
      pv[3] = (_Float16)accS[i][jt][3];
      *(h4*)(sP + hq * 136 + i * 16 + 4 * g) = pv;
    }
  }
  __syncthreads();

  f4 accO[4][2];
  for (int mt = 0; mt < 4; ++mt)
    for (int jt = 0; jt < 2; ++jt)
      for (int r = 0; r < 4; ++r) accO[mt][jt][r] = 0.f;
#pragma unroll
  for (int i2 = 0; i2 < 4; ++i2) {
    const int k = i2 * 32 + 8 * g;
    h8 av[4], pb[2];
#pragma unroll
    for (int mt = 0; mt < 4; ++mt)
      av[mt] = *(const h8*)(sVT + (mt * 16 + l16) * 136 + k);
#pragma unroll
    for (int jt = 0; jt < 2; ++jt)
      pb[jt] = *(const h8*)(sP + (wv * 32 + jt * 16 + l16) * 136 + k);
#pragma unroll
    for (int mt = 0; mt < 4; ++mt)
#pragma unroll
      for (int jt = 0; jt < 2; ++jt)
        accO[mt][jt] = MFMA32(av[mt], pb[jt], accO[mt][jt]);
  }

  __syncthreads();
#pragma unroll
  for (int mt = 0; mt < 4; ++mt)
#pragma unroll
    for (int jt = 0; jt < 2; ++jt)
#pragma unroll
      for (int r = 0; r < 4; ++r)
        sO[(wv * 32 + jt * 16 + l16) * 72 + mt * 16 + 4 * g + r] =
            (_Float16)(accO[mt][jt][r] * rinv[jt]);
  __syncthreads();

  const int hh = tid >> 1, d0 = (tid & 1) * 32;
  const _Float16* s = sO + hh * 72 + d0;
  _Float16* dst = attnout + ((long)bl * 16384 + hh * 128 + w) * 256 + head * 64 + d0;
#pragma unroll
  for (int e = 0; e < 4; ++e)
    *(u4*)(dst + e * 8) = *(const u4*)(s + e * 8);
}

// ---------------- K3: out[b][co][t] = Wproj^T[co][c]*attnout[t][c]+bproj --------
// (v9-proven)
__global__ __launch_bounds__(256, 4) void k3_proj(const _Float16* __restrict__ attnout,
                                                  const _Float16* __restrict__ wpt,
                                                  const float* __restrict__ bproj,
                                                  float* __restrict__ out,
                                                  int b_base, int nb) {
  const int ct = blockIdx.x, tt = blockIdx.y, bl = blockIdx.z;
  const int b = b_base + bl;
  const int tid = threadIdx.x;
  const int lane = tid & 63, wv = tid >> 6;
  const int g = lane >> 4, l16 = lane & 15;
  const int wr = wv >> 1, wc = wv & 1;
  const int co0 = ct * 128;
  const long t0 = (long)tt * 128;

  __shared__ __align__(16) char smem[33792];
  _Float16* sA = (_Float16*)smem;   // [128 co][64]
  _Float16* sB = sA + 128 * 64;     // [128 t][64]
  float* sOut = (float*)smem;       // reuse: [64][132] f32

  f4 acc[4][4];
#pragma unroll
  for (int mt = 0; mt < 4; ++mt)
#pragma unroll
    for (int nt = 0; nt < 4; ++nt)
#pragma unroll
      for (int r = 0; r < 4; ++r) acc[mt][nt][r] = 0.f;

  const _Float16* Ab = wpt + (long)co0 * 256;
  const _Float16* Bb = attnout + ((long)bl * 16384 + t0) * 256;
  const int r0 = wv * 32;
  const int rl = lane >> 3, ch = (lane & 7) * 8;

  for (int kc = 0; kc < 4; ++kc) {
    const int c0 = kc * 64;
#pragma unroll
    for (int i = 0; i < 4; ++i) {
      const int row = r0 + i * 8 + rl;
      gll16(Ab + (long)row * 256 + c0 + ch, sA + (r0 + i * 8) * 64);
      gll16(Bb + (long)row * 256 + c0 + ch, sB + (r0 + i * 8) * 64);
    }
    __syncthreads();
#pragma unroll
    for (int ks = 0; ks < 2; ++ks) {
      const int k = ks * 32 + 8 * g;
      h8 af[4], bf[4];
#pragma unroll
      for (int mt = 0; mt < 4; ++mt)
        af[mt] = *(const h8*)(sA + (wr * 64 + mt * 16 + l16) * 64 + k);
#pragma unroll
      for (int nt = 0; nt < 4; ++nt)
        bf[nt] = *(const h8*)(sB + (wc * 64 + nt * 16 + l16) * 64 + k);
#pragma unroll
      for (int mt = 0; mt < 4; ++mt)
#pragma unroll
        for (int nt = 0; nt < 4; ++nt)
          acc[mt][nt] = MFMA32(af[mt], bf[nt], acc[mt][nt]);
    }
    __syncthreads();
  }

#pragma unroll
  for (int h2 = 0; h2 < 2; ++h2) {
    if (h2) __syncthreads();
    if (wr == h2) {
#pragma unroll
      for (int mt = 0; mt < 4; ++mt) {
        f4 bb = *(const f4*)(bproj + co0 + h2 * 64 + mt * 16 + 4 * g);
#pragma unroll
        for (int nt = 0; nt < 4; ++nt)
#pragma unroll
          for (int r = 0; r < 4; ++r)
            sOut[(mt * 16 + 4 * g + r) * 132 + wc * 64 + nt * 16 + l16] =
                acc[mt][nt][r] + bb[r];
      }
    }
    __syncthreads();
    const int row = tid >> 2, seg = (tid & 3) * 32;
    const float* s = sOut + row * 132 + seg;
    float* dst = out + ((long)b * 256 + co0 + h2 * 64 + row) * 16384 + t0 + seg;
#pragma unroll
    for (int e = 0; e < 8; ++e)
      *(f4*)(dst + e * 4) = *(const f4*)(s + e * 4);
  }
}

// ---------------- launch ----------------
extern "C" void kernel_launch(void* const* d_in, const int* in_sizes, int n_in,
                              void* d_out, int out_size, void* d_ws, size_t ws_size,
                              hipStream_t stream) {
  const float* x = (const float*)d_in[0];
  const float* Wqkv = (const float*)d_in[1];
  const float* bqkv = (const float*)d_in[2];
  const float* Wproj = (const float*)d_in[3];
  const float* bproj = (const float*)d_in[4];
  float* out = (float*)d_out;

  char* ws = (char*)d_ws;
  // Layout: [wqt 384K][wpt 128K][qkv nb*24Mi][attnout nb*8Mi]
  const long WQT = 393216L, WPT = 131072L;
  const long PER_B = 25165824L + 8388608L;
  long nb_l = ((long)ws_size - (WQT + WPT)) / PER_B;
  int nb = nb_l < 1 ? 1 : (nb_l > 8 ? 8 : (int)nb_l);

  _Float16* wqt = (_Float16*)ws;
  _Float16* wpt = (_Float16*)(ws + WQT);
  _Float16* qkv = (_Float16*)(ws + WQT + WPT);
  _Float16* attnout = (_Float16*)(ws + WQT + WPT + (long)nb * 25165824L);

  prep_w<<<1024, 256, 0, stream>>>(Wqkv, Wproj, wqt, wpt);

  for (int b0 = 0; b0 < 8; b0 += nb) {
    int nbv = (8 - b0 < nb) ? (8 - b0) : nb;
    k1f<<<nbv * 256, 256, 0, stream>>>(x, wqt, bqkv, qkv, b0, nbv);
    k2_attn<<<dim3(128, 4, nbv), 256, 0, stream>>>(qkv, attnout, nbv);
    k3_proj<<<dim3(2, 128, nbv), 256, 0, stream>>>(attnout, wpt, bproj, out, b0, nbv);
  }
}